// Round 1
// baseline (31.218 us; speedup 1.0000x reference)
//
#include <hip/hip_runtime.h>
#include <hip/hip_bf16.h>

// Chebyshev positional embedding: out[row, n] = T_n(x), x = 2*id/max_seq_len - 1.
// Closed form T_n(x) = cos(n * acos(x)). Each thread produces 8 consecutive n
// (two float4 stores, perfectly coalesced). Base angle via sincosf, then 7
// angle-addition rotations with (cos t, sin t) = (x, sqrt(1-x^2)).
__global__ void __launch_bounds__(256)
cheb_kernel(const float* __restrict__ ids,
            const int* __restrict__ p_maxlen,
            float* __restrict__ out,
            int n_rows, int d_model) {
    const float inv = 2.0f / (float)(*p_maxlen);
    const int per_row = d_model >> 3;                 // threads per row (8 n's each)
    const long long total = (long long)n_rows * per_row;
    const long long stride = (long long)gridDim.x * blockDim.x;
    for (long long tid = (long long)blockIdx.x * blockDim.x + threadIdx.x;
         tid < total; tid += stride) {
        const int row = (int)(tid / per_row);
        const int seg = (int)(tid - (long long)row * per_row);

        float x = fmaf(ids[row], inv, -1.0f);
        x = fminf(fmaxf(x, -1.0f), 1.0f);             // guard acos domain
        const float sx = sqrtf(fmaxf(0.0f, 1.0f - x * x)); // sin(theta) >= 0
        const float theta = acosf(x);

        const int n0 = seg << 3;
        float c, s;
        sincosf((float)n0 * theta, &s, &c);           // cos/sin(n0*theta)

        float v[8];
#pragma unroll
        for (int k = 0; k < 8; ++k) {
            v[k] = c;
            // rotate by theta: cos((n+1)t) = c*x - s*sx ; sin((n+1)t) = s*x + c*sx
            const float nc = fmaf(c, x, -(s * sx));
            const float ns = fmaf(s, x,  (c * sx));
            c = nc; s = ns;
        }

        float4* o = (float4*)(out + tid * 8);
        o[0] = make_float4(v[0], v[1], v[2], v[3]);
        o[1] = make_float4(v[4], v[5], v[6], v[7]);
    }
}

extern "C" void kernel_launch(void* const* d_in, const int* in_sizes, int n_in,
                              void* d_out, int out_size, void* d_ws, size_t ws_size,
                              hipStream_t stream) {
    const float* ids     = (const float*)d_in[0];
    const int*   pmaxlen = (const int*)d_in[1];
    float*       out     = (float*)d_out;

    const int n_rows  = in_sizes[0];              // B*S = 32768
    const int d_model = out_size / n_rows;        // 1024

    const long long total = (long long)n_rows * (d_model >> 3); // work items
    int blocks = (int)((total + 255) / 256);
    if (blocks > 16384) blocks = 16384;

    cheb_kernel<<<blocks, 256, 0, stream>>>(ids, pmaxlen, out, n_rows, d_model);
}

// Round 2
// 26.396 us; speedup vs baseline: 1.1827x; 1.1827x over previous
//
#include <hip/hip_runtime.h>
#include <hip/hip_bf16.h>

#define INV2PI 0.15915494309189535f

// Fast path: d_model == 1024. One wave per row. Lane l owns n = 256*q + 4*l + {0..3},
// q = 0..3, so each float4 store is perfectly lane-coalesced (1 KB per wave per store).
// T_n(x) = cos(n*theta), theta = acos(x). Angles handled in REVOLUTIONS for the
// hardware v_sin_f32/v_cos_f32 (valid after v_fract reduction, per gfx950 ISA).
__global__ void __launch_bounds__(256)
cheb1024_kernel(const float* __restrict__ ids,
                const int* __restrict__ p_maxlen,
                float* __restrict__ out,
                int n_rows) {
    const float inv = 2.0f / (float)(*p_maxlen);
    const int wave = threadIdx.x >> 6;
    const int lane = threadIdx.x & 63;
    const int row  = blockIdx.x * 4 + wave;
    if (row >= n_rows) return;

    float x = fmaf(ids[row], inv, -1.0f);
    x = fminf(fmaxf(x, -1.0f), 1.0f);                  // acos domain guard
    const float sx = sqrtf(fmaxf(0.0f, 1.0f - x * x)); // sin(theta) >= 0
    const float trev = acosf(x) * INV2PI;              // theta in revolutions [0, 0.5]

    // base angle for this lane: n0 = 4*lane  (revolutions, fract-reduced, >= 0)
    float brev = (float)(4 * lane) * trev;
    brev -= floorf(brev);
    float bc = __builtin_amdgcn_cosf(brev);
    float bs = __builtin_amdgcn_sinf(brev);

    // cluster-advance rotation: 256*theta
    float crev = 256.0f * trev;
    crev -= floorf(crev);
    const float C = __builtin_amdgcn_cosf(crev);
    const float S = __builtin_amdgcn_sinf(crev);

    float* rowp = out + (size_t)row * 1024;
#pragma unroll
    for (int q = 0; q < 4; ++q) {
        // v_j = cos((n0 + 256q + j) * theta), j = 0..3, via rotation by theta
        const float v0 = bc;
        const float c1 = fmaf(bc, x, -(bs * sx));
        const float s1 = fmaf(bs, x,  (bc * sx));
        const float c2 = fmaf(c1, x, -(s1 * sx));
        const float s2 = fmaf(s1, x,  (c1 * sx));
        const float c3 = fmaf(c2, x, -(s2 * sx));

        ((float4*)(rowp + q * 256))[lane] = make_float4(v0, c1, c2, c3);

        // advance base by 256*theta
        const float nbc = fmaf(bc, C, -(bs * S));
        const float nbs = fmaf(bs, C,  (bc * S));
        bc = nbc; bs = nbs;
    }
}

// Generic fallback (any d_model % 8 == 0): round-1 kernel, kept for correctness
// on shapes the fast path doesn't cover.
__global__ void __launch_bounds__(256)
cheb_generic_kernel(const float* __restrict__ ids,
                    const int* __restrict__ p_maxlen,
                    float* __restrict__ out,
                    int n_rows, int d_model) {
    const float inv = 2.0f / (float)(*p_maxlen);
    const int per_row = d_model >> 3;
    const long long total = (long long)n_rows * per_row;
    const long long stride = (long long)gridDim.x * blockDim.x;
    for (long long tid = (long long)blockIdx.x * blockDim.x + threadIdx.x;
         tid < total; tid += stride) {
        const int row = (int)(tid / per_row);
        const int seg = (int)(tid - (long long)row * per_row);

        float x = fmaf(ids[row], inv, -1.0f);
        x = fminf(fmaxf(x, -1.0f), 1.0f);
        const float sx = sqrtf(fmaxf(0.0f, 1.0f - x * x));
        const float theta = acosf(x);

        float c, s;
        sincosf((float)(seg << 3) * theta, &s, &c);

        float v[8];
#pragma unroll
        for (int k = 0; k < 8; ++k) {
            v[k] = c;
            const float nc = fmaf(c, x, -(s * sx));
            const float ns = fmaf(s, x,  (c * sx));
            c = nc; s = ns;
        }
        float4* o = (float4*)(out + tid * 8);
        o[0] = make_float4(v[0], v[1], v[2], v[3]);
        o[1] = make_float4(v[4], v[5], v[6], v[7]);
    }
}

extern "C" void kernel_launch(void* const* d_in, const int* in_sizes, int n_in,
                              void* d_out, int out_size, void* d_ws, size_t ws_size,
                              hipStream_t stream) {
    const float* ids     = (const float*)d_in[0];
    const int*   pmaxlen = (const int*)d_in[1];
    float*       out     = (float*)d_out;

    const int n_rows  = in_sizes[0];           // B*S = 32768
    const int d_model = out_size / n_rows;     // 1024

    if (d_model == 1024) {
        const int blocks = (n_rows + 3) / 4;   // 4 rows (waves) per block
        cheb1024_kernel<<<blocks, 256, 0, stream>>>(ids, pmaxlen, out, n_rows);
    } else {
        const long long total = (long long)n_rows * (d_model >> 3);
        int blocks = (int)((total + 255) / 256);
        if (blocks > 16384) blocks = 16384;
        cheb_generic_kernel<<<blocks, 256, 0, stream>>>(ids, pmaxlen, out, n_rows, d_model);
    }
}